// Round 1
// baseline (41506.805 us; speedup 1.0000x reference)
//
#include <hip/hip_runtime.h>

#define TS 512
#define BB 256
#define ID 64
#define N0 306
#define N1 204
#define N2 2
#define D0 370
#define D1 510
#define D2 206

// d_ws layout (float offsets); all multiples of 4 for float4 alignment
#define OFF_W40 0            // 306*370*4 = 452880
#define OFF_W41 452880       // 204*510*4 = 416160
#define OFF_W42 869040       // 2*206*4   = 1648
#define OFF_B40 870688       // 306*4
#define OFF_B41 871912       // 204*4
#define OFF_B42 872728       // 2*4
#define OFF_HI0 872736       // 256*306
#define OFF_HI1 951072
#define OFF_HC0 1029408      // 256*204
#define OFF_HC1 1081632
#define OFF_HM0 1133856      // 256*2
#define OFF_HM1 1134368
// total 1134880 floats = 4.54 MB

__global__ __launch_bounds__(256) void prep_kernel(
    const float* __restrict__ h0,
    const float* __restrict__ f1w0, const float* __restrict__ f2w0,
    const float* __restrict__ taw0, const float* __restrict__ tbw0, const int* __restrict__ m0,
    const float* __restrict__ f1b0, const float* __restrict__ f2b0,
    const float* __restrict__ tab0, const float* __restrict__ tbb0,
    const float* __restrict__ f1w1, const float* __restrict__ f2w1,
    const float* __restrict__ taw1, const float* __restrict__ tbw1, const int* __restrict__ m1,
    const float* __restrict__ f1b1, const float* __restrict__ f2b1,
    const float* __restrict__ tab1, const float* __restrict__ tbb1,
    const float* __restrict__ f1w2, const float* __restrict__ f2w2,
    const float* __restrict__ taw2, const float* __restrict__ tbw2, const int* __restrict__ m2,
    const float* __restrict__ f1b2, const float* __restrict__ f2b2,
    const float* __restrict__ tab2, const float* __restrict__ tbb2,
    float* __restrict__ ws)
{
  const int A0 = N0*D0, A1 = N1*D1, A2 = N2*D2;
  int j = blockIdx.x*256 + threadIdx.x;
  if (j < A0) {
    float mm = (float)m0[j];
    ((float4*)(ws+OFF_W40))[j] = make_float4(f1w0[j]*mm, f2w0[j]*mm, taw0[j], tbw0[j]);
    return;
  }
  j -= A0;
  if (j < A1) {
    float mm = (float)m1[j];
    ((float4*)(ws+OFF_W41))[j] = make_float4(f1w1[j]*mm, f2w1[j]*mm, taw1[j], tbw1[j]);
    return;
  }
  j -= A1;
  if (j < A2) {
    float mm = (float)m2[j];
    ((float4*)(ws+OFF_W42))[j] = make_float4(f1w2[j]*mm, f2w2[j]*mm, taw2[j], tbw2[j]);
    return;
  }
  j -= A2;
  if (j < N0) { ((float4*)(ws+OFF_B40))[j] = make_float4(f1b0[j], f2b0[j], tab0[j], tbb0[j]); return; }
  j -= N0;
  if (j < N1) { ((float4*)(ws+OFF_B41))[j] = make_float4(f1b1[j], f2b1[j], tab1[j], tbb1[j]); return; }
  j -= N1;
  if (j < N2) { ((float4*)(ws+OFF_B42))[j] = make_float4(f1b2[j], f2b2[j], tab2[j], tbb2[j]); return; }
  j -= N2;
  if (j < BB*N0) { int r = j/N0, c = j - r*N0; (ws+OFF_HI1)[j] = h0[r*512 + c]; return; }
  j -= BB*N0;
  if (j < BB*N1) { int r = j/N1, c = j - r*N1; (ws+OFF_HC1)[j] = h0[r*512 + N0 + c]; return; }
  j -= BB*N1;
  if (j < BB*N2) { int r = j/N2, c = j - r*N2; (ws+OFF_HM1)[j] = h0[r*512 + N0 + N1 + c]; return; }
}

// stage0: hi(t) = cell0([x_t, hi(t-1)])
__global__ __launch_bounds__(256) void stage0_kernel(
    int t, const float* __restrict__ x,
    const float* __restrict__ W4, const float* __restrict__ B4,
    const float* __restrict__ hi_src, float* __restrict__ hi_dst)
{
  __shared__ float xs[16*371];
  int bid = blockIdx.x;
  int bt = bid >> 4, ut = bid & 15;
  int r0 = bt << 4;
  for (int i = threadIdx.x; i < 16*D0; i += 256) {
    int row = i / D0, col = i - row*D0;
    float v = (col < ID) ? x[((size_t)(r0+row)*TS + t)*ID + col]
                         : hi_src[(r0+row)*N0 + (col - ID)];
    xs[row*371 + col] = v;
  }
  __syncthreads();
  for (int k = 0; k < 2; ++k) {
    int p = (k << 8) + threadIdx.x;
    if (p >= 16*20) break;
    int ul = p >> 4, r = p & 15;
    int u = ut*20 + ul;
    if (u >= N0) continue;
    float a0=0.f, a1=0.f, a2=0.f, a3=0.f;
    const float4* wrow = (const float4*)W4 + (size_t)u*D0;
    const float* xr = xs + r*371;
    #pragma unroll 2
    for (int d = 0; d < D0; ++d) {
      float4 w = wrow[d];
      float xv = xr[d];
      a0 = fmaf(w.x, xv, a0); a1 = fmaf(w.y, xv, a1);
      a2 = fmaf(w.z, xv, a2); a3 = fmaf(w.w, xv, a3);
    }
    float4 b = ((const float4*)B4)[u];
    float f1 = tanhf(a0 + b.x);
    float f2 = tanhf(a1 + b.y);
    float tv = 1.f/(1.f + __expf((a2 + b.z) - (a3 + b.w)));  // sigmoid(tb - ta)
    hi_dst[(r0+r)*N0 + u] = f1*(1.f - tv) + tv*f2;
  }
}

// stage1: hc(t) = cell1([hi(t), hc(t-1)]); blocks 256..263 (t>0): hm(t-1) = cell2([hc(t-1), hm(t-2)])
__global__ __launch_bounds__(256) void stage1_kernel(
    int t,
    const float* __restrict__ W4, const float* __restrict__ B4,
    const float* __restrict__ W4m, const float* __restrict__ B4m,
    const float* __restrict__ hi_cur, const float* __restrict__ hc_src,
    float* __restrict__ hc_dst,
    const float* __restrict__ hm_src, float* __restrict__ hm_dst)
{
  int bid = blockIdx.x;
  if (bid < 256) {
    __shared__ float xs[16*511];
    int bt = bid >> 4, ut = bid & 15;
    int r0 = bt << 4;
    for (int i = threadIdx.x; i < 16*D1; i += 256) {
      int row = i / D1, col = i - row*D1;
      float v = (col < N0) ? hi_cur[(r0+row)*N0 + col]
                           : hc_src[(r0+row)*N1 + (col - N0)];
      xs[row*511 + col] = v;
    }
    __syncthreads();
    int p = threadIdx.x;
    if (p < 16*13) {
      int ul = p >> 4, r = p & 15;
      int u = ut*13 + ul;
      if (u < N1) {
        float a0=0.f, a1=0.f, a2=0.f, a3=0.f;
        const float4* wrow = (const float4*)W4 + (size_t)u*D1;
        const float* xr = xs + r*511;
        #pragma unroll 2
        for (int d = 0; d < D1; ++d) {
          float4 w = wrow[d];
          float xv = xr[d];
          a0 = fmaf(w.x, xv, a0); a1 = fmaf(w.y, xv, a1);
          a2 = fmaf(w.z, xv, a2); a3 = fmaf(w.w, xv, a3);
        }
        float4 b = ((const float4*)B4)[u];
        float f1 = tanhf(a0 + b.x);
        float f2 = tanhf(a1 + b.y);
        float tv = 1.f/(1.f + __expf((a2 + b.z) - (a3 + b.w)));
        hc_dst[(r0+r)*N1 + u] = f1*(1.f - tv) + tv*f2;
      }
    }
  } else if (t > 0 && threadIdx.x < 64) {
    int g = bid - 256;                  // 0..7
    int r = g*32 + (threadIdx.x >> 1);
    int u = threadIdx.x & 1;
    float a0=0.f, a1=0.f, a2=0.f, a3=0.f;
    const float4* wrow = (const float4*)W4m + (size_t)u*D2;
    const float* hcr = hc_src + r*N1;
    const float* hmr = hm_src + r*N2;
    for (int d = 0; d < D2; ++d) {
      float xv = (d < N1) ? hcr[d] : hmr[d - N1];
      float4 w = wrow[d];
      a0 = fmaf(w.x, xv, a0); a1 = fmaf(w.y, xv, a1);
      a2 = fmaf(w.z, xv, a2); a3 = fmaf(w.w, xv, a3);
    }
    float4 b = ((const float4*)B4m)[u];
    float f1 = tanhf(a0 + b.x);
    float f2 = tanhf(a1 + b.y);
    float tv = 1.f/(1.f + __expf((a2 + b.z) - (a3 + b.w)));
    hm_dst[r*N2 + u] = f1*(1.f - tv) + tv*f2;
  }
}

// final1: hm(T-1) + predictions
__global__ __launch_bounds__(256) void final1_kernel(
    const float* __restrict__ W4m, const float* __restrict__ B4m,
    const float* __restrict__ hc_cur, const float* __restrict__ hm_src,
    const float* __restrict__ fcw, const float* __restrict__ fcb,
    float* __restrict__ out, float* __restrict__ hm_out)
{
  int r = threadIdx.x;  // one row per thread, single block of 256
  float m[2];
  for (int u = 0; u < 2; ++u) {
    float a0=0.f, a1=0.f, a2=0.f, a3=0.f;
    const float4* wrow = (const float4*)W4m + (size_t)u*D2;
    for (int d = 0; d < D2; ++d) {
      float xv = (d < N1) ? hc_cur[r*N1 + d] : hm_src[r*N2 + d - N1];
      float4 w = wrow[d];
      a0 = fmaf(w.x, xv, a0); a1 = fmaf(w.y, xv, a1);
      a2 = fmaf(w.z, xv, a2); a3 = fmaf(w.w, xv, a3);
    }
    float4 b = ((const float4*)B4m)[u];
    float f1 = tanhf(a0 + b.x);
    float f2 = tanhf(a1 + b.y);
    float tv = 1.f/(1.f + __expf((a2 + b.z) - (a3 + b.w)));
    m[u] = f1*(1.f - tv) + tv*f2;
    hm_out[r*2 + u] = m[u];
  }
  out[r*2 + 0] = m[0]*fcw[0] + m[1]*fcw[1] + fcb[0];
  out[r*2 + 1] = m[0]*fcw[2] + m[1]*fcw[3] + fcb[1];
}

// final2: pack h = [hi, hc, hm]
__global__ __launch_bounds__(256) void final2_kernel(
    const float* __restrict__ hi, const float* __restrict__ hc,
    const float* __restrict__ hm, float* __restrict__ out)
{
  int i = blockIdx.x*256 + threadIdx.x;
  if (i >= BB*512) return;
  int r = i >> 9, c = i & 511;
  float v;
  if (c < N0)           v = hi[r*N0 + c];
  else if (c < N0+N1)   v = hc[r*N1 + c - N0];
  else                  v = hm[r*N2 + c - (N0+N1)];
  out[512 + i] = v;
}

extern "C" void kernel_launch(void* const* d_in, const int* in_sizes, int n_in,
                              void* d_out, int out_size, void* d_ws, size_t ws_size,
                              hipStream_t stream) {
  const float* x    = (const float*)d_in[0];
  const float* h0   = (const float*)d_in[1];
  const float* f1w0 = (const float*)d_in[2];
  const float* f1b0 = (const float*)d_in[3];
  const float* f2w0 = (const float*)d_in[4];
  const float* f2b0 = (const float*)d_in[5];
  const float* taw0 = (const float*)d_in[6];
  const float* tab0 = (const float*)d_in[7];
  const float* tbw0 = (const float*)d_in[8];
  const float* tbb0 = (const float*)d_in[9];
  const int*   m0   = (const int*)d_in[10];
  const float* f1w1 = (const float*)d_in[11];
  const float* f1b1 = (const float*)d_in[12];
  const float* f2w1 = (const float*)d_in[13];
  const float* f2b1 = (const float*)d_in[14];
  const float* taw1 = (const float*)d_in[15];
  const float* tab1 = (const float*)d_in[16];
  const float* tbw1 = (const float*)d_in[17];
  const float* tbb1 = (const float*)d_in[18];
  const int*   m1   = (const int*)d_in[19];
  const float* f1w2 = (const float*)d_in[20];
  const float* f1b2 = (const float*)d_in[21];
  const float* f2w2 = (const float*)d_in[22];
  const float* f2b2 = (const float*)d_in[23];
  const float* taw2 = (const float*)d_in[24];
  const float* tab2 = (const float*)d_in[25];
  const float* tbw2 = (const float*)d_in[26];
  const float* tbb2 = (const float*)d_in[27];
  const int*   m2   = (const int*)d_in[28];
  const float* fcw  = (const float*)d_in[29];
  const float* fcb  = (const float*)d_in[30];

  float* ws  = (float*)d_ws;
  float* out = (float*)d_out;

  float* W40 = ws + OFF_W40; float* B40 = ws + OFF_B40;
  float* W41 = ws + OFF_W41; float* B41 = ws + OFF_B41;
  float* W42 = ws + OFF_W42; float* B42 = ws + OFF_B42;
  float* hib[2] = { ws + OFF_HI0, ws + OFF_HI1 };
  float* hcb[2] = { ws + OFF_HC0, ws + OFF_HC1 };
  float* hmb[2] = { ws + OFF_HM0, ws + OFF_HM1 };

  prep_kernel<<<1365, 256, 0, stream>>>(
      h0,
      f1w0, f2w0, taw0, tbw0, m0, f1b0, f2b0, tab0, tbb0,
      f1w1, f2w1, taw1, tbw1, m1, f1b1, f2b1, tab1, tbb1,
      f1w2, f2w2, taw2, tbw2, m2, f1b2, f2b2, tab2, tbb2,
      ws);

  for (int t = 0; t < TS; ++t) {
    // hi(t): read hib[(t+1)&1] (= hi(t-1)), write hib[t&1]
    stage0_kernel<<<256, 256, 0, stream>>>(t, x, W40, B40, hib[(t+1)&1], hib[t&1]);
    // hc(t): read hi(t)=hib[t&1], hc(t-1)=hcb[(t+1)&1], write hcb[t&1]
    // hm(t-1): read hc(t-1)=hcb[(t+1)&1], hm(t-2)=hmb[t&1], write hmb[(t+1)&1]
    stage1_kernel<<<264, 256, 0, stream>>>(t, W41, B41, W42, B42,
                                           hib[t&1], hcb[(t+1)&1], hcb[t&1],
                                           hmb[t&1], hmb[(t+1)&1]);
  }
  // after loop: hi(511)=hib[1], hc(511)=hcb[1], hm(510)=hmb[0]
  final1_kernel<<<1, 256, 0, stream>>>(W42, B42, hcb[1], hmb[0], fcw, fcb, out, hmb[1]);
  final2_kernel<<<512, 256, 0, stream>>>(hib[1], hcb[1], hmb[1], out);
}